// Round 10
// baseline (790.186 us; speedup 1.0000x reference)
//
#include <hip/hip_runtime.h>

#define N_NODES  500000
#define HIDDEN   256
#define N_GRAPHS 8192

typedef float f32x4 __attribute__((ext_vector_type(4)));
typedef short s16x8 __attribute__((ext_vector_type(8)));

__device__ __forceinline__ unsigned short f2bf(float f) {
    unsigned int u = __float_as_uint(f);
    u += 0x7fffu + ((u >> 16) & 1u);   // RNE round to bf16
    return (unsigned short)(u >> 16);
}

// Pack W1 [K=256][N=256] fp32 into bf16 B-fragments, grouped per wave-slice.
// slot = (wave*8 + kt)*4 + ntp ; nt = wave*4 + ntp
// w1pack[(slot*64 + lane)*8 + j] = bf16( W1[kt*32 + (lane>>4)*8 + j][nt*16 + (lane&15)] )
__global__ void prep_w1_kernel(const float* __restrict__ W1,
                               unsigned short* __restrict__ w1pack) {
    int tid  = blockIdx.x * 256 + threadIdx.x;   // 0..8191
    int lane = tid & 63;
    int slot = tid >> 6;                         // 0..127
    int wv   = slot >> 5;
    int kt   = (slot >> 2) & 7;
    int ntp  = slot & 3;
    int nt   = wv * 4 + ntp;
    int krow = kt * 32 + ((lane >> 4) & 3) * 8;
    int col  = nt * 16 + (lane & 15);
    unsigned short tmp[8];
#pragma unroll
    for (int j = 0; j < 8; ++j)
        tmp[j] = f2bf(W1[(size_t)(krow + j) * 256 + col]);
    *(uint4*)(w1pack + (size_t)tid * 8) = *(const uint4*)tmp;
}

// offsEnd[g] = lower_bound(batch, g+1)  (end of graph g's sorted range)
__global__ void offsets_kernel(const int* __restrict__ batch,
                               int* __restrict__ offsEnd) {
    int g = blockIdx.x * 256 + threadIdx.x;      // 0..8191
    if (g >= N_GRAPHS) return;
    int lo = 0, hi = N_NODES;
    while (lo < hi) {
        int mid = (lo + hi) >> 1;
        if (batch[mid] < g + 1) lo = mid + 1; else hi = mid;
    }
    offsEnd[g] = lo;
}

// One block per GRAPH, 256 threads = 4 waves. No atomics: block owns its output row.
// amdgpu_waves_per_eu(4,4): pin allocator to 4 waves/EU (128 VGPR). With
// __launch_bounds__(256,4) (min-only) LLVM targeted 8 waves -> 64 VGPR and
// spilled the chunk-loop state: rounds 7/9 showed WRITE ~= FETCH ~= 1.4 GB.
__launch_bounds__(256)
__attribute__((amdgpu_waves_per_eu(4, 4)))
__global__ void attn_pool_graph(const float* __restrict__ x,
                                const float* __restrict__ b1,
                                const float* __restrict__ W2,
                                const float* __restrict__ b2,
                                const unsigned short* __restrict__ w1pack,
                                const int* __restrict__ offsEnd,
                                float* __restrict__ out) {
    __shared__ unsigned short xbf[64 * 256];   // 32 KiB bf16 chunk, unit-swizzled
    __shared__ float plds[256];                // logit partials [wave][row]
    __shared__ float accs[4 * 256];            // final cross-wave numerator
    __shared__ float dsum[4];                  // final cross-wave denominator

    const int tid  = threadIdx.x;
    const int wave = tid >> 6;
    const int lane = tid & 63;
    const int cl   = lane & 15;
    const int kgrp = lane >> 4;
    const int g    = blockIdx.x;

    const int nend    = offsEnd[g];
    const int nstart  = (g == 0) ? 0 : offsEnd[g - 1];
    const int nchunks = (nend - nstart + 63) >> 6;

    float b1c[4], w2c[4];
#pragma unroll
    for (int ntp = 0; ntp < 4; ++ntp) {
        int nt = wave * 4 + ntp;
        b1c[ntp] = b1[nt * 16 + cl];
        w2c[ntp] = W2[nt * 16 + cl];
    }
    const float b2v = b2[0];

    f32x4 accv = {0.f, 0.f, 0.f, 0.f};
    float accden = 0.f;

    for (int c = 0; c < nchunks; ++c) {
        const int cbase = nstart + c * 64;

        // ---- stage chunk -> bf16 LDS; 16B-unit index ^= (row&7) ----
#pragma unroll
        for (int i = 0; i < 8; ++i) {
            int v   = tid + i * 256;      // 0..2047
            int row = v >> 5;
            int cu  = v & 31;
            f32x4 a = {0.f, 0.f, 0.f, 0.f}, cc = {0.f, 0.f, 0.f, 0.f};
            int node = cbase + row;
            if (node < nend) {
                const float* p = x + (size_t)node * HIDDEN + cu * 8;
                a  = *(const f32x4*)p;
                cc = *(const f32x4*)(p + 4);
            }
            s16x8 w;
            w[0] = (short)f2bf(a[0]);  w[1] = (short)f2bf(a[1]);
            w[2] = (short)f2bf(a[2]);  w[3] = (short)f2bf(a[3]);
            w[4] = (short)f2bf(cc[0]); w[5] = (short)f2bf(cc[1]);
            w[6] = (short)f2bf(cc[2]); w[7] = (short)f2bf(cc[3]);
            *(s16x8*)(xbf + (size_t)(row * 32 + (cu ^ (row & 7))) * 8) = w;
        }
        __syncthreads();

        // ---- GEMM + tanh, two column-halves (acc = 32 regs each pass) ----
        float sj[4][4];
#pragma unroll
        for (int rt = 0; rt < 4; ++rt)
#pragma unroll
            for (int j = 0; j < 4; ++j) sj[rt][j] = 0.f;

#pragma unroll
        for (int half = 0; half < 2; ++half) {
            f32x4 acc2[4][2];
#pragma unroll
            for (int rt = 0; rt < 4; ++rt)
#pragma unroll
                for (int p = 0; p < 2; ++p)
                    acc2[rt][p] = (f32x4){0.f, 0.f, 0.f, 0.f};

#pragma unroll
            for (int kt = 0; kt < 8; ++kt) {
                s16x8 bf[2];
#pragma unroll
                for (int p = 0; p < 2; ++p)
                    bf[p] = *(const s16x8*)(w1pack +
                        ((size_t)(((wave * 8 + kt) * 4 + half * 2 + p) * 64 + lane) << 3));
#pragma unroll
                for (int rt = 0; rt < 4; ++rt) {
                    int row = rt * 16 + cl;
                    int cu  = kt * 4 + kgrp;
                    s16x8 af = *(const s16x8*)(xbf +
                        (size_t)(row * 32 + (cu ^ (row & 7))) * 8);
#pragma unroll
                    for (int p = 0; p < 2; ++p)
                        acc2[rt][p] = __builtin_amdgcn_mfma_f32_16x16x32_bf16(
                            af, bf[p], acc2[rt][p], 0, 0, 0);
                }
            }

            // tanh + partial logit for these 32 cols
#pragma unroll
            for (int rt = 0; rt < 4; ++rt)
#pragma unroll
                for (int p = 0; p < 2; ++p) {
                    float bb = b1c[half * 2 + p];
                    float ww = w2c[half * 2 + p];
#pragma unroll
                    for (int j = 0; j < 4; ++j) {
                        float h = acc2[rt][p][j] + bb;
                        h = fminf(fmaxf(h, -15.f), 15.f);
                        float e2 = __expf(2.f * h);
                        float th = (e2 - 1.f) * __builtin_amdgcn_rcpf(e2 + 1.f);
                        sj[rt][j] += th * ww;
                    }
                }
        }

        // reduce across 16 lanes of each kgrp group
#pragma unroll
        for (int m = 1; m < 16; m <<= 1)
#pragma unroll
            for (int rt = 0; rt < 4; ++rt)
#pragma unroll
                for (int j = 0; j < 4; ++j)
                    sj[rt][j] += __shfl_xor(sj[rt][j], m, 64);
        if (cl == 0) {
#pragma unroll
            for (int rt = 0; rt < 4; ++rt)
#pragma unroll
                for (int j = 0; j < 4; ++j)
                    plds[wave * 64 + rt * 16 + kgrp * 4 + j] = sj[rt][j];
        }
        __syncthreads();

        // ---- combine partials -> e per row (masked past nend) ----
        int rr = wave * 16 + cl;
        float logit = plds[rr] + plds[64 + rr] + plds[128 + rr] + plds[192 + rr] + b2v;
        float el = (cbase + rr < nend) ? __expf(logit) : 0.f;

        // ---- weighted accumulation; x re-read fp32 (L2-hot, just staged) ----
#pragma unroll
        for (int r = 0; r < 16; ++r) {
            int node = cbase + wave * 16 + r;
            if (node < nend) {         // wave-uniform branch
                float er = __shfl(el, r, 64);
                f32x4 xv = *(const f32x4*)(x + (size_t)node * HIDDEN + lane * 4);
                accv += er * xv;
                accden += er;
            }
        }
        // 2 barriers/chunk: xbf reads all precede the plds barrier; next-chunk
        // xbf writes follow it; plds(c+1) writes are fenced by barrier B1(c+1).
    }

    // ---- cross-wave reduction + single output write ----
    *(f32x4*)(accs + wave * 256 + lane * 4) = accv;
    if (lane == 0) dsum[wave] = accden;
    __syncthreads();
    if (wave == 0) {
        f32x4 t0 = *(const f32x4*)(accs + lane * 4);
        f32x4 t1 = *(const f32x4*)(accs + 256 + lane * 4);
        f32x4 t2 = *(const f32x4*)(accs + 512 + lane * 4);
        f32x4 t3 = *(const f32x4*)(accs + 768 + lane * 4);
        float d = dsum[0] + dsum[1] + dsum[2] + dsum[3] + 1e-8f;
        f32x4 tot = t0 + t1 + t2 + t3;
        f32x4 res;
        res[0] = tot[0] / d; res[1] = tot[1] / d;
        res[2] = tot[2] / d; res[3] = tot[3] / d;
        *(f32x4*)(out + (size_t)g * HIDDEN + lane * 4) = res;
    }
}

extern "C" void kernel_launch(void* const* d_in, const int* in_sizes, int n_in,
                              void* d_out, int out_size, void* d_ws, size_t ws_size,
                              hipStream_t stream) {
    const float* x     = (const float*)d_in[0];
    const int*   batch = (const int*)d_in[1];
    const float* W1    = (const float*)d_in[2];
    const float* b1    = (const float*)d_in[3];
    const float* W2    = (const float*)d_in[4];
    const float* b2    = (const float*)d_in[5];
    float* out = (float*)d_out;

    unsigned short* w1pack = (unsigned short*)d_ws;          // 128 KiB
    int* offsEnd = (int*)((char*)d_ws + 131072);             // 32 KiB (8192 ints)

    prep_w1_kernel<<<32, 256, 0, stream>>>(W1, w1pack);
    offsets_kernel<<<32, 256, 0, stream>>>(batch, offsEnd);

    attn_pool_graph<<<N_GRAPHS, 256, 0, stream>>>(x, b1, W2, b2, w1pack, offsEnd, out);
}

// Round 11
// 708.392 us; speedup vs baseline: 1.1155x; 1.1155x over previous
//
#include <hip/hip_runtime.h>

#define N_NODES  500000
#define HIDDEN   256
#define N_GRAPHS 8192

typedef float f32x4 __attribute__((ext_vector_type(4)));
typedef short s16x8 __attribute__((ext_vector_type(8)));

__device__ __forceinline__ unsigned short f2bf(float f) {
    unsigned int u = __float_as_uint(f);
    u += 0x7fffu + ((u >> 16) & 1u);   // RNE round to bf16
    return (unsigned short)(u >> 16);
}

// Pack W1 [K=256][N=256] fp32 into bf16 B-fragments, grouped per wave-slice.
// slot = (wave*8 + kt)*4 + ntp ; nt = wave*4 + ntp
// w1pack[(slot*64 + lane)*8 + j] = bf16( W1[kt*32 + (lane>>4)*8 + j][nt*16 + (lane&15)] )
__global__ void prep_w1_kernel(const float* __restrict__ W1,
                               unsigned short* __restrict__ w1pack) {
    int tid  = blockIdx.x * 256 + threadIdx.x;   // 0..8191
    int lane = tid & 63;
    int slot = tid >> 6;                         // 0..127
    int wv   = slot >> 5;
    int kt   = (slot >> 2) & 7;
    int ntp  = slot & 3;
    int nt   = wv * 4 + ntp;
    int krow = kt * 32 + ((lane >> 4) & 3) * 8;
    int col  = nt * 16 + (lane & 15);
    unsigned short tmp[8];
#pragma unroll
    for (int j = 0; j < 8; ++j)
        tmp[j] = f2bf(W1[(size_t)(krow + j) * 256 + col]);
    *(uint4*)(w1pack + (size_t)tid * 8) = *(const uint4*)tmp;
}

// offsEnd[g] = lower_bound(batch, g+1)  (end of graph g's sorted range)
__global__ void offsets_kernel(const int* __restrict__ batch,
                               int* __restrict__ offsEnd) {
    int g = blockIdx.x * 256 + threadIdx.x;      // 0..8191
    if (g >= N_GRAPHS) return;
    int lo = 0, hi = N_NODES;
    while (lo < hi) {
        int mid = (lo + hi) >> 1;
        if (batch[mid] < g + 1) lo = mid + 1; else hi = mid;
    }
    offsEnd[g] = lo;
}

// One block per GRAPH, 256 threads = 4 waves. No atomics: block owns its output row.
// __launch_bounds__(256,3): 3 waves/EU -> ~170 unified VGPR budget. At 4 waves/EU
// (rounds 7/9/10) the 128-reg budget spilled the chunk loop: WRITE~=FETCH~=1.4GB.
// Cross-chunk accumulators live in LDS (accs/dsum), not registers.
__launch_bounds__(256, 3)
__global__ void attn_pool_graph(const float* __restrict__ x,
                                const float* __restrict__ b1,
                                const float* __restrict__ W2,
                                const float* __restrict__ b2,
                                const unsigned short* __restrict__ w1pack,
                                const int* __restrict__ offsEnd,
                                float* __restrict__ out) {
    __shared__ unsigned short xbf[64 * 256];   // 32 KiB bf16 chunk, unit-swizzled
    __shared__ float plds[256];                // logit partials [wave][row]
    __shared__ float accs[4 * 256];            // cross-chunk numerator [wave][lane*4]
    __shared__ float dsum[4];                  // cross-chunk denominator [wave]

    const int tid  = threadIdx.x;
    const int wave = tid >> 6;
    const int lane = tid & 63;
    const int cl   = lane & 15;
    const int kgrp = lane >> 4;
    const int g    = blockIdx.x;

    const int nend    = offsEnd[g];
    const int nstart  = (g == 0) ? 0 : offsEnd[g - 1];
    const int nchunks = (nend - nstart + 63) >> 6;

    // init LDS accumulators (each thread owns its slot; no barrier needed yet)
    *(f32x4*)(accs + tid * 4) = (f32x4){0.f, 0.f, 0.f, 0.f};
    if (tid < 4) dsum[tid] = 0.f;

    float b1c[4], w2c[4];
#pragma unroll
    for (int ntp = 0; ntp < 4; ++ntp) {
        int nt = wave * 4 + ntp;
        b1c[ntp] = b1[nt * 16 + cl];
        w2c[ntp] = W2[nt * 16 + cl];
    }
    const float b2v = b2[0];

    for (int c = 0; c < nchunks; ++c) {
        const int cbase = nstart + c * 64;

        // ---- stage chunk -> bf16 LDS; 16B-unit index ^= (row&7) ----
#pragma unroll
        for (int i = 0; i < 8; ++i) {
            int v   = tid + i * 256;      // 0..2047
            int row = v >> 5;
            int cu  = v & 31;
            f32x4 a = {0.f, 0.f, 0.f, 0.f}, cc = {0.f, 0.f, 0.f, 0.f};
            int node = cbase + row;
            if (node < nend) {
                const float* p = x + (size_t)node * HIDDEN + cu * 8;
                a  = *(const f32x4*)p;
                cc = *(const f32x4*)(p + 4);
            }
            s16x8 w;
            w[0] = (short)f2bf(a[0]);  w[1] = (short)f2bf(a[1]);
            w[2] = (short)f2bf(a[2]);  w[3] = (short)f2bf(a[3]);
            w[4] = (short)f2bf(cc[0]); w[5] = (short)f2bf(cc[1]);
            w[6] = (short)f2bf(cc[2]); w[7] = (short)f2bf(cc[3]);
            *(s16x8*)(xbf + (size_t)(row * 32 + (cu ^ (row & 7))) * 8) = w;
        }
        __syncthreads();

        // ---- GEMM + tanh, two column-halves (acc = 32 regs each pass) ----
        float sj[4][4];
#pragma unroll
        for (int rt = 0; rt < 4; ++rt)
#pragma unroll
            for (int j = 0; j < 4; ++j) sj[rt][j] = 0.f;

#pragma unroll
        for (int half = 0; half < 2; ++half) {
            f32x4 acc2[4][2];
#pragma unroll
            for (int rt = 0; rt < 4; ++rt)
#pragma unroll
                for (int p = 0; p < 2; ++p)
                    acc2[rt][p] = (f32x4){0.f, 0.f, 0.f, 0.f};

#pragma unroll
            for (int kt = 0; kt < 8; ++kt) {
                s16x8 bf[2];
#pragma unroll
                for (int p = 0; p < 2; ++p)
                    bf[p] = *(const s16x8*)(w1pack +
                        ((size_t)(((wave * 8 + kt) * 4 + half * 2 + p) * 64 + lane) << 3));
#pragma unroll
                for (int rt = 0; rt < 4; ++rt) {
                    int row = rt * 16 + cl;
                    int cu  = kt * 4 + kgrp;
                    s16x8 af = *(const s16x8*)(xbf +
                        (size_t)(row * 32 + (cu ^ (row & 7))) * 8);
#pragma unroll
                    for (int p = 0; p < 2; ++p)
                        acc2[rt][p] = __builtin_amdgcn_mfma_f32_16x16x32_bf16(
                            af, bf[p], acc2[rt][p], 0, 0, 0);
                }
            }

            // tanh + partial logit for these 32 cols
#pragma unroll
            for (int rt = 0; rt < 4; ++rt)
#pragma unroll
                for (int p = 0; p < 2; ++p) {
                    float bb = b1c[half * 2 + p];
                    float ww = w2c[half * 2 + p];
#pragma unroll
                    for (int j = 0; j < 4; ++j) {
                        float h = acc2[rt][p][j] + bb;
                        h = fminf(fmaxf(h, -15.f), 15.f);
                        float e2 = __expf(2.f * h);
                        float th = (e2 - 1.f) * __builtin_amdgcn_rcpf(e2 + 1.f);
                        sj[rt][j] += th * ww;
                    }
                }
        }

        // reduce across 16 lanes of each kgrp group
#pragma unroll
        for (int m = 1; m < 16; m <<= 1)
#pragma unroll
            for (int rt = 0; rt < 4; ++rt)
#pragma unroll
                for (int j = 0; j < 4; ++j)
                    sj[rt][j] += __shfl_xor(sj[rt][j], m, 64);
        if (cl == 0) {
#pragma unroll
            for (int rt = 0; rt < 4; ++rt)
#pragma unroll
                for (int j = 0; j < 4; ++j)
                    plds[wave * 64 + rt * 16 + kgrp * 4 + j] = sj[rt][j];
        }
        __syncthreads();

        // ---- combine partials -> e per row (masked past nend) ----
        int rr = wave * 16 + cl;
        float logit = plds[rr] + plds[64 + rr] + plds[128 + rr] + plds[192 + rr] + b2v;
        float el = (cbase + rr < nend) ? __expf(logit) : 0.f;

        // ---- weighted accumulation; x re-read fp32 (L2-hot, just staged) ----
        f32x4 accv = {0.f, 0.f, 0.f, 0.f};
        float accden = 0.f;
#pragma unroll
        for (int r = 0; r < 16; ++r) {
            int node = cbase + wave * 16 + r;
            if (node < nend) {         // wave-uniform branch
                float er = __shfl(el, r, 64);
                f32x4 xv = *(const f32x4*)(x + (size_t)node * HIDDEN + lane * 4);
                accv += er * xv;
                accden += er;
            }
        }
        // fold this chunk into the LDS accumulators (own slots only)
        *(f32x4*)(accs + wave * 256 + lane * 4) =
            *(const f32x4*)(accs + wave * 256 + lane * 4) + accv;
        if (lane == 0) dsum[wave] += accden;
        // 2 barriers/chunk: xbf reads all precede the plds barrier; next-chunk
        // xbf writes follow it; plds(c+1) writes are fenced by barrier B1(c+1).
    }

    // ---- cross-wave reduction + single output write ----
    __syncthreads();
    if (wave == 0) {
        f32x4 t0 = *(const f32x4*)(accs + lane * 4);
        f32x4 t1 = *(const f32x4*)(accs + 256 + lane * 4);
        f32x4 t2 = *(const f32x4*)(accs + 512 + lane * 4);
        f32x4 t3 = *(const f32x4*)(accs + 768 + lane * 4);
        float d = dsum[0] + dsum[1] + dsum[2] + dsum[3] + 1e-8f;
        f32x4 tot = t0 + t1 + t2 + t3;
        f32x4 res;
        res[0] = tot[0] / d; res[1] = tot[1] / d;
        res[2] = tot[2] / d; res[3] = tot[3] / d;
        *(f32x4*)(out + (size_t)g * HIDDEN + lane * 4) = res;
    }
}

extern "C" void kernel_launch(void* const* d_in, const int* in_sizes, int n_in,
                              void* d_out, int out_size, void* d_ws, size_t ws_size,
                              hipStream_t stream) {
    const float* x     = (const float*)d_in[0];
    const int*   batch = (const int*)d_in[1];
    const float* W1    = (const float*)d_in[2];
    const float* b1    = (const float*)d_in[3];
    const float* W2    = (const float*)d_in[4];
    const float* b2    = (const float*)d_in[5];
    float* out = (float*)d_out;

    unsigned short* w1pack = (unsigned short*)d_ws;          // 128 KiB
    int* offsEnd = (int*)((char*)d_ws + 131072);             // 32 KiB (8192 ints)

    prep_w1_kernel<<<32, 256, 0, stream>>>(W1, w1pack);
    offsets_kernel<<<32, 256, 0, stream>>>(batch, offsEnd);

    attn_pool_graph<<<N_GRAPHS, 256, 0, stream>>>(x, b1, W2, b2, w1pack, offsEnd, out);
}

// Round 12
// 284.096 us; speedup vs baseline: 2.7814x; 2.4935x over previous
//
#include <hip/hip_runtime.h>

#define N_NODES  500000
#define HIDDEN   256
#define N_GRAPHS 8192
#define NTILES   ((N_NODES + 63) / 64)   // 7813

typedef float f32x4 __attribute__((ext_vector_type(4)));
typedef short s16x8 __attribute__((ext_vector_type(8)));

__device__ __forceinline__ unsigned short f2bf(float f) {
    unsigned int u = __float_as_uint(f);
    u += 0x7fffu + ((u >> 16) & 1u);   // RNE round to bf16
    return (unsigned short)(u >> 16);
}

// Pack W1 [K=256][N=256] fp32 into bf16 B-fragments, grouped per wave-slice.
// slot = (wave*8 + kt)*4 + ntp ; nt = wave*4 + ntp
// w1pack[(slot*64 + lane)*8 + j] = bf16( W1[kt*32 + (lane>>4)*8 + j][nt*16 + (lane&15)] )
__global__ void prep_w1_kernel(const float* __restrict__ W1,
                               unsigned short* __restrict__ w1pack) {
    int tid  = blockIdx.x * 256 + threadIdx.x;   // 0..8191
    int lane = tid & 63;
    int slot = tid >> 6;                         // 0..127
    int wv   = slot >> 5;
    int kt   = (slot >> 2) & 7;
    int ntp  = slot & 3;
    int nt   = wv * 4 + ntp;
    int krow = kt * 32 + ((lane >> 4) & 3) * 8;
    int col  = nt * 16 + (lane & 15);
    unsigned short tmp[8];
#pragma unroll
    for (int j = 0; j < 8; ++j)
        tmp[j] = f2bf(W1[(size_t)(krow + j) * 256 + col]);
    *(uint4*)(w1pack + (size_t)tid * 8) = *(const uint4*)tmp;
}

// offsEnd[g] = lower_bound(batch, g+1)  (end of graph g's sorted range)
__global__ void offsets_kernel(const int* __restrict__ batch,
                               int* __restrict__ offsEnd) {
    int g = blockIdx.x * 256 + threadIdx.x;      // 0..8191
    if (g >= N_GRAPHS) return;
    int lo = 0, hi = N_NODES;
    while (lo < hi) {
        int mid = (lo + hi) >> 1;
        if (batch[mid] < g + 1) lo = mid + 1; else hi = mid;
    }
    offsEnd[g] = lo;
}

// Kernel A: per 64-node tile, straight-line (round-6 GEMM body, proven no-spill).
// Computes e[node] = exp(W2.tanh(x W1 + b1) + b2). No atomics, no chunk loop.
__launch_bounds__(256, 4)
__global__ void logits_kernel(const float* __restrict__ x,
                              const float* __restrict__ b1,
                              const float* __restrict__ W2,
                              const float* __restrict__ b2,
                              const unsigned short* __restrict__ w1pack,
                              float* __restrict__ evals) {
    __shared__ unsigned short xbf[64 * 256];   // 32 KiB bf16 tile, unit-swizzled
    __shared__ float plds[256];                // logit partials [wave][row]
    __shared__ float elds[64];                 // e per row (for coalesced write)

    const int tid  = threadIdx.x;
    const int wave = tid >> 6;
    const int lane = tid & 63;
    const int cl   = lane & 15;
    const int kgrp = lane >> 4;
    const int base = blockIdx.x * 64;

    // ---- stage tile -> bf16 LDS; 16B-unit index ^= (row&7) ----
#pragma unroll
    for (int i = 0; i < 8; ++i) {
        int v   = tid + i * 256;      // 0..2047
        int row = v >> 5;
        int cu  = v & 31;
        f32x4 a = {0.f, 0.f, 0.f, 0.f}, cc = {0.f, 0.f, 0.f, 0.f};
        int node = base + row;
        if (node < N_NODES) {
            const float* p = x + (size_t)node * HIDDEN + cu * 8;
            a  = *(const f32x4*)p;
            cc = *(const f32x4*)(p + 4);
        }
        s16x8 w;
        w[0] = (short)f2bf(a[0]);  w[1] = (short)f2bf(a[1]);
        w[2] = (short)f2bf(a[2]);  w[3] = (short)f2bf(a[3]);
        w[4] = (short)f2bf(cc[0]); w[5] = (short)f2bf(cc[1]);
        w[6] = (short)f2bf(cc[2]); w[7] = (short)f2bf(cc[3]);
        *(s16x8*)(xbf + (size_t)(row * 32 + (cu ^ (row & 7))) * 8) = w;
    }

    float b1c[4], w2c[4];
#pragma unroll
    for (int ntp = 0; ntp < 4; ++ntp) {
        int nt = wave * 4 + ntp;
        b1c[ntp] = b1[nt * 16 + cl];
        w2c[ntp] = W2[nt * 16 + cl];
    }
    const float b2v = b2[0];
    __syncthreads();

    // ---- GEMM: acc[rt][ntp] straight-line (AGPR-resident, no spill) ----
    f32x4 acc[4][4];
#pragma unroll
    for (int rt = 0; rt < 4; ++rt)
#pragma unroll
        for (int ntp = 0; ntp < 4; ++ntp)
            acc[rt][ntp] = (f32x4){0.f, 0.f, 0.f, 0.f};

#pragma unroll
    for (int kt = 0; kt < 8; ++kt) {
        s16x8 bf[4];
#pragma unroll
        for (int ntp = 0; ntp < 4; ++ntp)
            bf[ntp] = *(const s16x8*)(w1pack +
                ((size_t)(((wave * 8 + kt) * 4 + ntp) * 64 + lane) << 3));
#pragma unroll
        for (int rt = 0; rt < 4; ++rt) {
            int row = rt * 16 + cl;
            int cu  = kt * 4 + kgrp;
            s16x8 af = *(const s16x8*)(xbf +
                (size_t)(row * 32 + (cu ^ (row & 7))) * 8);
#pragma unroll
            for (int ntp = 0; ntp < 4; ++ntp)
                acc[rt][ntp] = __builtin_amdgcn_mfma_f32_16x16x32_bf16(
                    af, bf[ntp], acc[rt][ntp], 0, 0, 0);
        }
    }

    // ---- tanh + partial logit over this wave's 64 cols ----
    float sj[4][4];
#pragma unroll
    for (int rt = 0; rt < 4; ++rt)
#pragma unroll
        for (int j = 0; j < 4; ++j) sj[rt][j] = 0.f;
#pragma unroll
    for (int rt = 0; rt < 4; ++rt)
#pragma unroll
        for (int ntp = 0; ntp < 4; ++ntp)
#pragma unroll
            for (int j = 0; j < 4; ++j) {
                float h = acc[rt][ntp][j] + b1c[ntp];
                h = fminf(fmaxf(h, -15.f), 15.f);
                float e2 = __expf(2.f * h);
                float th = (e2 - 1.f) * __builtin_amdgcn_rcpf(e2 + 1.f);
                sj[rt][j] += th * w2c[ntp];
            }
#pragma unroll
    for (int m = 1; m < 16; m <<= 1)
#pragma unroll
        for (int rt = 0; rt < 4; ++rt)
#pragma unroll
            for (int j = 0; j < 4; ++j)
                sj[rt][j] += __shfl_xor(sj[rt][j], m, 64);
    if (cl == 0) {
#pragma unroll
        for (int rt = 0; rt < 4; ++rt)
#pragma unroll
            for (int j = 0; j < 4; ++j)
                plds[wave * 64 + rt * 16 + kgrp * 4 + j] = sj[rt][j];
    }
    __syncthreads();

    // ---- combine 4 waves' partials -> e per row; coalesced e write ----
    int rr = wave * 16 + cl;
    float logit = plds[rr] + plds[64 + rr] + plds[128 + rr] + plds[192 + rr] + b2v;
    if (kgrp == 0) elds[rr] = __expf(logit);
    __syncthreads();
    if (tid < 64 && base + tid < N_NODES) evals[base + tid] = elds[tid];
}

// Kernel B: one block per graph, pure streaming weighted segment-sum.
// Thread t's column-group (t&63) is invariant under the +256 unit stride.
__launch_bounds__(256)
__global__ void segsum_kernel(const float* __restrict__ x,
                              const float* __restrict__ evals,
                              const int* __restrict__ offsEnd,
                              float* __restrict__ out) {
    __shared__ float accs[256 * 4];
    __shared__ float dlds[4];

    const int tid = threadIdx.x;
    const int g   = blockIdx.x;
    const int nend   = offsEnd[g];
    const int nstart = (g == 0) ? 0 : offsEnd[g - 1];

    f32x4 acc = {0.f, 0.f, 0.f, 0.f};
    float den = 0.f;
    const long uend = (long)nend * 64;     // f32x4 units
    for (long i = (long)nstart * 64 + tid; i < uend; i += 256) {
        int   row = (int)(i >> 6);
        float er  = evals[row];
        f32x4 xv  = *(const f32x4*)(x + i * 4);
        acc += er * xv;
        den += er;
    }
    // phase p = tid>>6 covers rows r ≡ p (mod 4); den identical within a phase
    *(f32x4*)(accs + tid * 4) = acc;
    if ((tid & 63) == 0) dlds[tid >> 6] = den;
    __syncthreads();
    if (tid < 64) {
        f32x4 t0 = *(const f32x4*)(accs + tid * 4);
        f32x4 t1 = *(const f32x4*)(accs + (tid + 64) * 4);
        f32x4 t2 = *(const f32x4*)(accs + (tid + 128) * 4);
        f32x4 t3 = *(const f32x4*)(accs + (tid + 192) * 4);
        float d  = dlds[0] + dlds[1] + dlds[2] + dlds[3] + 1e-8f;
        f32x4 tot = t0 + t1 + t2 + t3;
        f32x4 res;
        res[0] = tot[0] / d; res[1] = tot[1] / d;
        res[2] = tot[2] / d; res[3] = tot[3] / d;
        *(f32x4*)(out + (size_t)g * HIDDEN + tid * 4) = res;
    }
}

extern "C" void kernel_launch(void* const* d_in, const int* in_sizes, int n_in,
                              void* d_out, int out_size, void* d_ws, size_t ws_size,
                              hipStream_t stream) {
    const float* x     = (const float*)d_in[0];
    const int*   batch = (const int*)d_in[1];
    const float* W1    = (const float*)d_in[2];
    const float* b1    = (const float*)d_in[3];
    const float* W2    = (const float*)d_in[4];
    const float* b2    = (const float*)d_in[5];
    float* out = (float*)d_out;

    unsigned short* w1pack = (unsigned short*)d_ws;              // 128 KiB
    int*   offsEnd = (int*)((char*)d_ws + 131072);               // 32 KiB
    float* evals   = (float*)((char*)d_ws + 163840);             // 2 MB (500k fp32)

    prep_w1_kernel<<<32, 256, 0, stream>>>(W1, w1pack);
    offsets_kernel<<<32, 256, 0, stream>>>(batch, offsEnd);

    logits_kernel<<<NTILES, 256, 0, stream>>>(x, b1, W2, b2, w1pack, evals);
    segsum_kernel<<<N_GRAPHS, 256, 0, stream>>>(x, evals, offsEnd, out);
}

// Round 13
// 269.202 us; speedup vs baseline: 2.9353x; 1.0553x over previous
//
#include <hip/hip_runtime.h>

#define N_NODES  500000
#define HIDDEN   256
#define N_GRAPHS 8192
#define NTILES   ((N_NODES + 63) / 64)   // 7813
#define NWIN     (N_NODES / 16)          // 31250 (N_NODES % 16 == 0)
#define PROW     260                     // 256 num + 1 den + pad (16B-aligned rows)

typedef float f32x4 __attribute__((ext_vector_type(4)));
typedef short s16x8 __attribute__((ext_vector_type(8)));

__device__ __forceinline__ unsigned short f2bf(float f) {
    unsigned int u = __float_as_uint(f);
    u += 0x7fffu + ((u >> 16) & 1u);   // RNE round to bf16
    return (unsigned short)(u >> 16);
}

// Pack W1 [K=256][N=256] fp32 into bf16 B-fragments, grouped per wave-slice.
__global__ void prep_w1_kernel(const float* __restrict__ W1,
                               unsigned short* __restrict__ w1pack) {
    int tid  = blockIdx.x * 256 + threadIdx.x;   // 0..8191
    int lane = tid & 63;
    int slot = tid >> 6;                         // 0..127
    int wv   = slot >> 5;
    int kt   = (slot >> 2) & 7;
    int ntp  = slot & 3;
    int nt   = wv * 4 + ntp;
    int krow = kt * 32 + ((lane >> 4) & 3) * 8;
    int col  = nt * 16 + (lane & 15);
    unsigned short tmp[8];
#pragma unroll
    for (int j = 0; j < 8; ++j)
        tmp[j] = f2bf(W1[(size_t)(krow + j) * 256 + col]);
    *(uint4*)(w1pack + (size_t)tid * 8) = *(const uint4*)tmp;
}

// offsEnd[g] = lower_bound(batch, g+1)
__global__ void offsets_kernel(const int* __restrict__ batch,
                               int* __restrict__ offsEnd) {
    int g = blockIdx.x * 256 + threadIdx.x;
    if (g >= N_GRAPHS) return;
    int lo = 0, hi = N_NODES;
    while (lo < hi) {
        int mid = (lo + hi) >> 1;
        if (batch[mid] < g + 1) lo = mid + 1; else hi = mid;
    }
    offsEnd[g] = lo;
}

// Fused: per 64-node tile. GEMM -> logits -> e; then per-wave 16-row window
// segment walk. Segments fully inside a window: direct out write (unique owner).
// Straddling segments: one partial to pre[w] / suf[w]. No atomics, no chunk loop.
__launch_bounds__(256, 4)
__global__ void fused_kernel(const float* __restrict__ x,
                             const int*   __restrict__ batch,
                             const float* __restrict__ b1,
                             const float* __restrict__ W2,
                             const float* __restrict__ b2,
                             const unsigned short* __restrict__ w1pack,
                             float* __restrict__ preW,
                             float* __restrict__ sufW,
                             float* __restrict__ out) {
    __shared__ unsigned short xbf[64 * 256];   // 32 KiB bf16 tile, unit-swizzled
    __shared__ float plds[256];                // logit partials [wave][row]

    const int tid  = threadIdx.x;
    const int wave = tid >> 6;
    const int lane = tid & 63;
    const int cl   = lane & 15;
    const int kgrp = lane >> 4;
    const int base = blockIdx.x * 64;

    // ---- stage tile -> bf16 LDS; 16B-unit index ^= (row&7) ----
#pragma unroll
    for (int i = 0; i < 8; ++i) {
        int v   = tid + i * 256;
        int row = v >> 5;
        int cu  = v & 31;
        f32x4 a = {0.f, 0.f, 0.f, 0.f}, cc = {0.f, 0.f, 0.f, 0.f};
        int node = base + row;
        if (node < N_NODES) {
            const float* p = x + (size_t)node * HIDDEN + cu * 8;
            a  = *(const f32x4*)p;
            cc = *(const f32x4*)(p + 4);
        }
        s16x8 w;
        w[0] = (short)f2bf(a[0]);  w[1] = (short)f2bf(a[1]);
        w[2] = (short)f2bf(a[2]);  w[3] = (short)f2bf(a[3]);
        w[4] = (short)f2bf(cc[0]); w[5] = (short)f2bf(cc[1]);
        w[6] = (short)f2bf(cc[2]); w[7] = (short)f2bf(cc[3]);
        *(s16x8*)(xbf + (size_t)(row * 32 + (cu ^ (row & 7))) * 8) = w;
    }

    float b1c[4], w2c[4];
#pragma unroll
    for (int ntp = 0; ntp < 4; ++ntp) {
        int nt = wave * 4 + ntp;
        b1c[ntp] = b1[nt * 16 + cl];
        w2c[ntp] = W2[nt * 16 + cl];
    }
    const float b2v = b2[0];
    __syncthreads();

    // ---- GEMM (straight-line, AGPR acc) ----
    f32x4 acc[4][4];
#pragma unroll
    for (int rt = 0; rt < 4; ++rt)
#pragma unroll
        for (int ntp = 0; ntp < 4; ++ntp)
            acc[rt][ntp] = (f32x4){0.f, 0.f, 0.f, 0.f};

#pragma unroll
    for (int kt = 0; kt < 8; ++kt) {
        s16x8 bf[4];
#pragma unroll
        for (int ntp = 0; ntp < 4; ++ntp)
            bf[ntp] = *(const s16x8*)(w1pack +
                ((size_t)(((wave * 8 + kt) * 4 + ntp) * 64 + lane) << 3));
#pragma unroll
        for (int rt = 0; rt < 4; ++rt) {
            int row = rt * 16 + cl;
            int cu  = kt * 4 + kgrp;
            s16x8 af = *(const s16x8*)(xbf +
                (size_t)(row * 32 + (cu ^ (row & 7))) * 8);
#pragma unroll
            for (int ntp = 0; ntp < 4; ++ntp)
                acc[rt][ntp] = __builtin_amdgcn_mfma_f32_16x16x32_bf16(
                    af, bf[ntp], acc[rt][ntp], 0, 0, 0);
        }
    }

    // ---- tanh + partial logit ----
    float sj[4][4];
#pragma unroll
    for (int rt = 0; rt < 4; ++rt)
#pragma unroll
        for (int j = 0; j < 4; ++j) sj[rt][j] = 0.f;
#pragma unroll
    for (int rt = 0; rt < 4; ++rt)
#pragma unroll
        for (int ntp = 0; ntp < 4; ++ntp)
#pragma unroll
            for (int j = 0; j < 4; ++j) {
                float h = acc[rt][ntp][j] + b1c[ntp];
                h = fminf(fmaxf(h, -15.f), 15.f);
                float e2 = __expf(2.f * h);
                float th = (e2 - 1.f) * __builtin_amdgcn_rcpf(e2 + 1.f);
                sj[rt][j] += th * w2c[ntp];
            }
#pragma unroll
    for (int m = 1; m < 16; m <<= 1)
#pragma unroll
        for (int rt = 0; rt < 4; ++rt)
#pragma unroll
            for (int j = 0; j < 4; ++j)
                sj[rt][j] += __shfl_xor(sj[rt][j], m, 64);
    if (cl == 0) {
#pragma unroll
        for (int rt = 0; rt < 4; ++rt)
#pragma unroll
            for (int j = 0; j < 4; ++j)
                plds[wave * 64 + rt * 16 + kgrp * 4 + j] = sj[rt][j];
    }
    __syncthreads();

    // ---- e per row ----
    int rr = wave * 16 + cl;
    float logit = plds[rr] + plds[64 + rr] + plds[128 + rr] + plds[192 + rr] + b2v;
    float el = __expf(logit);

    // ---- per-window (16-row) segment walk ----
    const int ws = base + wave * 16;            // window start (global row)
    if (ws < N_NODES) {                          // full window (N % 16 == 0)
        const int wid = ws >> 4;                 // global window id
        int bval = batch[ws + cl];               // row cl's graph (cl<16 meaningful)
        const int gfirst = __shfl(bval, 0, 64);
        const int glast  = __shfl(bval, 15, 64);
        const bool eb = (ws > 0) && (batch[ws - 1] == gfirst);          // extends back
        const bool ef = (ws + 16 < N_NODES) && (batch[ws + 16] == glast); // extends fwd

        f32x4 accv = {0.f, 0.f, 0.f, 0.f};
        float accden = 0.f;
        int gcur = gfirst, sl = 0;
#pragma unroll
        for (int r = 0; r < 16; ++r) {
            int   g  = __shfl(bval, r, 64);
            float er = __shfl(el, r, 64);
            if (g != gcur) {                     // wave-uniform: flush (not final)
                bool sb = (sl == 0) && eb;
                if (!sb) {                       // fully inside window -> final
                    float d = accden + 1e-8f;
                    f32x4 res;
                    res[0] = accv[0] / d; res[1] = accv[1] / d;
                    res[2] = accv[2] / d; res[3] = accv[3] / d;
                    *(f32x4*)(out + (size_t)gcur * HIDDEN + lane * 4) = res;
                } else {                         // continues from prev window
                    *(f32x4*)(preW + (size_t)wid * PROW + lane * 4) = accv;
                    if (lane == 0) preW[(size_t)wid * PROW + 256] = accden;
                }
                accv = (f32x4){0.f, 0.f, 0.f, 0.f};
                accden = 0.f;
                gcur = g; sl = r;
            }
            f32x4 xv = *(const f32x4*)(x + (size_t)(ws + r) * HIDDEN + lane * 4);
            accv += er * xv;
            accden += er;
        }
        // final flush
        {
            bool sb = (sl == 0) && eb;
            bool ea = ef;
            if (!sb && !ea) {                    // fully inside window
                float d = accden + 1e-8f;
                f32x4 res;
                res[0] = accv[0] / d; res[1] = accv[1] / d;
                res[2] = accv[2] / d; res[3] = accv[3] / d;
                *(f32x4*)(out + (size_t)gcur * HIDDEN + lane * 4) = res;
            } else if (!sb && sl > 0) {          // starts mid-window, continues fwd
                *(f32x4*)(sufW + (size_t)wid * PROW + lane * 4) = accv;
                if (lane == 0) sufW[(size_t)wid * PROW + 256] = accden;
            } else {                             // covers window start
                *(f32x4*)(preW + (size_t)wid * PROW + lane * 4) = accv;
                if (lane == 0) preW[(size_t)wid * PROW + 256] = accden;
            }
        }
    }
}

// Combine: one wave per graph. Straddlers (w0<w1): sum window partials.
// Empty graphs: zeros. Single-window graphs were direct-written by fused_kernel.
__launch_bounds__(256)
__global__ void combine_kernel(const float* __restrict__ preW,
                               const float* __restrict__ sufW,
                               const int* __restrict__ offsEnd,
                               float* __restrict__ out) {
    const int g    = blockIdx.x * 4 + (threadIdx.x >> 6);
    const int lane = threadIdx.x & 63;
    if (g >= N_GRAPHS) return;
    const int s = (g == 0) ? 0 : offsEnd[g - 1];
    const int e = offsEnd[g];
    if (e == s) {                                // empty graph -> zeros
        *(f32x4*)(out + (size_t)g * HIDDEN + lane * 4) = (f32x4){0.f, 0.f, 0.f, 0.f};
        return;
    }
    const int w0 = s >> 4, w1 = (e - 1) >> 4;
    if (w0 == w1) return;                        // direct-written

    const float* row = (s > (w0 << 4)) ? sufW + (size_t)w0 * PROW
                                       : preW + (size_t)w0 * PROW;
    f32x4 acc = *(const f32x4*)(row + lane * 4);
    float den = row[256];
    for (int w = w0 + 1; w <= w1; ++w) {
        const float* pr = preW + (size_t)w * PROW;
        acc += *(const f32x4*)(pr + lane * 4);
        den += pr[256];
    }
    float d = den + 1e-8f;
    f32x4 res;
    res[0] = acc[0] / d; res[1] = acc[1] / d;
    res[2] = acc[2] / d; res[3] = acc[3] / d;
    *(f32x4*)(out + (size_t)g * HIDDEN + lane * 4) = res;
}

extern "C" void kernel_launch(void* const* d_in, const int* in_sizes, int n_in,
                              void* d_out, int out_size, void* d_ws, size_t ws_size,
                              hipStream_t stream) {
    const float* x     = (const float*)d_in[0];
    const int*   batch = (const int*)d_in[1];
    const float* W1    = (const float*)d_in[2];
    const float* b1    = (const float*)d_in[3];
    const float* W2    = (const float*)d_in[4];
    const float* b2    = (const float*)d_in[5];
    float* out = (float*)d_out;

    unsigned short* w1pack = (unsigned short*)d_ws;                  // 128 KiB
    int*   offsEnd = (int*)((char*)d_ws + 131072);                   // 32 KiB
    float* preW    = (float*)((char*)d_ws + 163840);                 // 32.5 MB
    float* sufW    = (float*)((char*)d_ws + 163840 + (size_t)NWIN * PROW * 4);

    prep_w1_kernel<<<32, 256, 0, stream>>>(W1, w1pack);
    offsets_kernel<<<32, 256, 0, stream>>>(batch, offsEnd);

    fused_kernel<<<NTILES, 256, 0, stream>>>(x, batch, b1, W2, b2, w1pack,
                                             preW, sufW, out);
    combine_kernel<<<(N_GRAPHS + 3) / 4, 256, 0, stream>>>(preW, sufW, offsEnd, out);
}